// Round 3
// baseline (451.529 us; speedup 1.0000x reference)
//
#include <hip/hip_runtime.h>

#define DI __device__ __forceinline__

typedef __attribute__((ext_vector_type(8))) short short8;
typedef __attribute__((ext_vector_type(4))) float f32x4;
typedef unsigned short u16;
typedef unsigned int u32;

DI u16 f2bf(float f) {
  union { float f; u32 u; } v; v.f = f;
  u32 r = v.u + 0x7FFFu + ((v.u >> 16) & 1u);
  return (u16)(r >> 16);
}
DI float bf2f(u16 h) {
  union { u32 u; float f; } v; v.u = ((u32)h) << 16; return v.f;
}
DI f32x4 mfma16(short8 a, short8 b, f32x4 c) {
  return __builtin_amdgcn_mfma_f32_16x16x32_bf16(a, b, c, 0, 0, 0);
}

// ---------------- problem constants ----------------
// B=32, S=2048, STATE=64, LATENT=128, ENC=256, INPUT_DIM=320, TOK=65536
// scan: C=8 chunk length, P=256 chunks, 2 KS carry levels (A^8, A^16);
// truncation ~||A^32|| ~ 1e-8 << 6.4e-3 tolerance (rho(A)~0.577).

// ---------------- workspace layout (bytes) ----------------
static const size_t OFF_H0   = 0;                       // 65536*256 bf16 = 32 MB (enc h0 / dec g0)
static const size_t OFF_H1   = 33554432;                // 65536*256 bf16 = 32 MB (enc h1 / dec g1)
static const size_t OFF_ZB   = 67108864;                // 65536*128 bf16 = 16 MB
static const size_t OFF_HB   = 83886080;                // 65536*128 bf16 = 16 MB (scan out)
static const size_t OFF_LB   = 100663296;               // 65536*128 bf16 = 16 MB  [t][b][k]
static const size_t OFF_WT   = 117440512;               // 229376 bf16 transposed weights
static const size_t OFF_POWR = 117899264;               // 17*16384 f32 (A^j, j=1..16)
static const size_t OFF_POWT = 119013376;               // 17*16384 bf16 (A^j transposed [n][k])
static const size_t OFF_ST   = 119570432;               // 256 f32 stats
static const size_t OFF_YB   = 119571456;               // 256*32*128 bf16 raw chunk carries
static const size_t OFF_G1   = 121668608;               // 256*32*128 bf16 KS level-1
static const size_t OFF_INS  = 123765760;               // 256*32*128 bf16 resolved carries

// wt element offsets
#define OW0 0
#define OW1 16384
#define OW2 81920
#define OD0 114688
#define OD1 147456
#define OD2 212992

// ---------------- weight convert: bf16, transposed [n][k]; also seed A^1 ----------------
__global__ __launch_bounds__(256) void convw_k(const float* __restrict__ ew0, const float* __restrict__ ew1,
                                               const float* __restrict__ ew2, const float* __restrict__ dw0,
                                               const float* __restrict__ dw1, const float* __restrict__ dw2,
                                               const float* __restrict__ Aw, u16* __restrict__ wt,
                                               float* __restrict__ powR, u16* __restrict__ powT) {
  int idx = blockIdx.x * 256 + threadIdx.x;
  if (idx < 16384) { int n = idx >> 6, k = idx & 63;  wt[OW0 + idx] = f2bf(ew0[k * 256 + n]); return; }
  idx -= 16384;
  if (idx < 65536) { int n = idx >> 8, k = idx & 255; wt[OW1 + idx] = f2bf(ew1[k * 256 + n]); return; }
  idx -= 65536;
  if (idx < 32768) { int n = idx >> 8, k = idx & 255; wt[OW2 + idx] = f2bf(ew2[k * 128 + n]); return; }
  idx -= 32768;
  if (idx < 32768) { int n = idx >> 7, k = idx & 127; wt[OD0 + idx] = f2bf(dw0[k * 256 + n]); return; }
  idx -= 32768;
  if (idx < 65536) { int n = idx >> 8, k = idx & 255; wt[OD1 + idx] = f2bf(dw1[k * 256 + n]); return; }
  idx -= 65536;
  if (idx < 16384) { int n = idx >> 8, k = idx & 255; wt[OD2 + idx] = f2bf(dw2[k * 64 + n]); return; }
  idx -= 16384;
  { int k = idx >> 7, n = idx & 127;
    powR[16384 + idx] = Aw[idx];
    powT[16384 + n * 128 + k] = f2bf(Aw[idx]); }
}

// ---------------- no-LDS MFMA GEMM: OUT[M][NTOT] = act(A[M][K] @ W[K][N] + b) ----------------
// All fragments direct global->VGPR (weights are L2-resident, A rows lane-private).
// Block tile 128 x NB; 4 waves in 2x2 (wm x wn), wave tile 64 x NB/2. No barriers.
template <int K, int NB, int LDA, int AOFF, bool AFP32, bool RELU, bool F32OUT>
__global__ __launch_bounds__(256) void gemm_k(const void* __restrict__ Ap, const u16* __restrict__ WT,
                                              const float* __restrict__ bias, u16* __restrict__ outB,
                                              float* __restrict__ outF, int NTOT) {
  const int tid = threadIdx.x, w = tid >> 6, l = tid & 63, lm = l & 15, lq = l >> 4;
  const int wm = w & 1, wn = w >> 1;
  const int m0 = blockIdx.x * 128 + wm * 64;
  const int n0 = blockIdx.y * NB + wn * (NB / 2);
  constexpr int NT = NB / 32;
  constexpr int KS = K / 32;
  const u16* Ab = (const u16*)Ap;
  const float* Af = (const float*)Ap;
  f32x4 acc[4][NT];
#pragma unroll
  for (int mt = 0; mt < 4; mt++)
#pragma unroll
    for (int nt = 0; nt < NT; nt++) acc[mt][nt] = (f32x4){0.f, 0.f, 0.f, 0.f};
#pragma unroll
  for (int ks = 0; ks < KS; ks++) {
    const int k0 = ks * 32 + lq * 8;
    short8 af[4];
#pragma unroll
    for (int mt = 0; mt < 4; mt++) {
      const size_t row = (size_t)(m0 + mt * 16 + lm);
      if constexpr (AFP32) {
        const float* p = Af + row * LDA + AOFF + k0;
        float4 f0 = *(const float4*)p, f1 = *(const float4*)(p + 4);
        short8 t;
        t[0] = (short)f2bf(f0.x); t[1] = (short)f2bf(f0.y);
        t[2] = (short)f2bf(f0.z); t[3] = (short)f2bf(f0.w);
        t[4] = (short)f2bf(f1.x); t[5] = (short)f2bf(f1.y);
        t[6] = (short)f2bf(f1.z); t[7] = (short)f2bf(f1.w);
        af[mt] = t;
      } else {
        af[mt] = *(const short8*)&Ab[row * LDA + k0];
      }
    }
#pragma unroll
    for (int nt = 0; nt < NT; nt++) {
      short8 bfr = *(const short8*)&WT[(size_t)(n0 + nt * 16 + lm) * K + k0];
#pragma unroll
      for (int mt = 0; mt < 4; mt++) acc[mt][nt] = mfma16(af[mt], bfr, acc[mt][nt]);
    }
  }
#pragma unroll
  for (int nt = 0; nt < NT; nt++) {
    const int n = n0 + nt * 16 + lm;
    const float bv = bias[n];
#pragma unroll
    for (int mt = 0; mt < 4; mt++) {
#pragma unroll
      for (int r = 0; r < 4; r++) {
        const int m = m0 + mt * 16 + lq * 4 + r;
        float v = acc[mt][nt][r] + bv;
        if (RELU) v = fmaxf(v, 0.f);
        if (F32OUT) outF[(size_t)m * NTOT + n] = v;
        else outB[(size_t)m * NTOT + n] = f2bf(v);
      }
    }
  }
}

// ---------------- BN stats: per-channel sum / sumsq via per-block partials + atomics ----------------
__global__ __launch_bounds__(256) void stats_k(const u16* __restrict__ zb, float* __restrict__ st) {
  __shared__ float s1[256], s2[256];
  const int tid = threadIdx.x, ch = tid & 127, half = tid >> 7;
  const size_t base = (size_t)blockIdx.x * 256;
  float a = 0.f, b = 0.f;
  for (int i = half; i < 256; i += 2) {
    float v = bf2f(zb[(base + i) * 128 + ch]);
    a += v; b += v * v;
  }
  s1[tid] = a; s2[tid] = b;
  __syncthreads();
  if (tid < 128) {
    atomicAdd(&st[ch], s1[tid] + s1[tid + 128]);
    atomicAdd(&st[128 + ch], s2[tid] + s2[tid + 128]);
  }
}

// ---------------- finalize: mean/var -> normalized z[:,0,:] = chunk-0 carry seed ----------------
__global__ __launch_bounds__(128) void finalize_k(const float* __restrict__ st, const u16* __restrict__ zb,
                                                  const float* __restrict__ gam, const float* __restrict__ bet,
                                                  u16* __restrict__ yb) {
  const int ch = threadIdx.x;
  const float mean = st[ch] * (1.f / 65536.f);
  const float var = st[128 + ch] * (1.f / 65536.f) - mean * mean;
  const float sc = rsqrtf(var + 1e-5f) * gam[ch];
  const float sh = bet[ch] - mean * sc;
  for (int b = 0; b < 32; b++) {
    float z = bf2f(zb[(size_t)b * 2048 * 128 + ch]);
    yb[b * 128 + ch] = f2bf(z * sc + sh);
  }
}

// ---------------- matrix powers (fp32): A^{p+mi+1} = A^p * A^{mi+1} ----------------
__global__ __launch_bounds__(256) void pow_round_k(float* __restrict__ powR, u16* __restrict__ powT,
                                                   int p, int mi_base) {
  const int mi = mi_base + (blockIdx.x >> 2), nc = blockIdx.x & 3;
  const float* Rp = powR + (size_t)p * 16384;
  const float* Rm = powR + (size_t)(mi + 1) * 16384;
  float* Ro = powR + (size_t)(p + mi + 1) * 16384;
  u16* To = powT + (size_t)(p + mi + 1) * 16384;
  __shared__ __align__(16) float RpS[128 * 132];
  __shared__ __align__(16) float RmS[128 * 36];
  const int tid = threadIdx.x;
  for (int i = tid; i < 4096; i += 256) {
    int r = i >> 5, c4 = i & 31;
    *(float4*)&RpS[r * 132 + c4 * 4] = *(const float4*)&Rp[r * 128 + c4 * 4];
  }
  for (int i = tid; i < 1024; i += 256) {
    int r = i >> 3, c4 = i & 7;
    *(float4*)&RmS[r * 36 + c4 * 4] = *(const float4*)&Rm[r * 128 + nc * 32 + c4 * 4];
  }
  __syncthreads();
  const int tc = tid & 7, tr = tid >> 3;
  float acc[4][4];
#pragma unroll
  for (int i = 0; i < 4; i++)
#pragma unroll
    for (int j = 0; j < 4; j++) acc[i][j] = 0.f;
  for (int kk = 0; kk < 128; kk++) {
    const float4 bv = *(const float4*)&RmS[kk * 36 + tc * 4];
#pragma unroll
    for (int i = 0; i < 4; i++) {
      const float av = RpS[(tr * 4 + i) * 132 + kk];
      acc[i][0] += av * bv.x; acc[i][1] += av * bv.y;
      acc[i][2] += av * bv.z; acc[i][3] += av * bv.w;
    }
  }
#pragma unroll
  for (int i = 0; i < 4; i++)
#pragma unroll
    for (int j = 0; j < 4; j++) {
      const int row = tr * 4 + i, col = nc * 32 + tc * 4 + j;
      Ro[row * 128 + col] = acc[i][j];
      To[col * 128 + row] = f2bf(acc[i][j]);
    }
}

// ---------------- phase 1: local scans, 256 chunks x 8 steps, bu computed on the fly ----------------
__global__ __launch_bounds__(256) void phase1_k(const float* __restrict__ in, const float* __restrict__ Bd,
                                                const u16* __restrict__ powT, u16* __restrict__ lb,
                                                u16* __restrict__ yb) {
  __shared__ __align__(16) u16 hS[2][32 * 136];
  __shared__ __align__(16) u16 buS[32 * 136];
  const int tid = threadIdx.x, c = blockIdx.x;
  const int w = tid >> 6, l = tid & 63, lm = l & 15, lq = l >> 4;
  const u16* T1 = powT + 16384;  // A^T
  short8 bfr[2][4];
#pragma unroll
  for (int nt = 0; nt < 2; nt++)
#pragma unroll
    for (int ks = 0; ks < 4; ks++) {
      int n = (w * 2 + nt) * 16 + lm, k0 = ks * 32 + lq * 8;
      bfr[nt][ks] = *(const short8*)&T1[n * 128 + k0];
    }
  // staging lanes: rows r0, r0+16; cols ch*8..ch*8+8 of the u-part
  const int r0 = tid >> 4, ch = tid & 15;
  float dv[8];
#pragma unroll
  for (int j = 0; j < 8; j++) {
    float d = Bd[ch * 8 + j];
    dv[j] = fminf(0.95f, fmaxf(-0.95f, d));
  }
  const float* u0 = in + (size_t)r0 * 2048 * 320 + (size_t)(c * 8) * 320 + 192 + ch * 8;
  const float* u1 = in + (size_t)(r0 + 16) * 2048 * 320 + (size_t)(c * 8) * 320 + 192 + ch * 8;
  float4 p0 = *(const float4*)u0, p0b = *(const float4*)(u0 + 4);
  float4 p1 = *(const float4*)u1, p1b = *(const float4*)(u1 + 4);
  for (int tau = 0; tau < 8; tau++) {
    const int t = c * 8 + tau;
    short8 s0, s1;
    s0[0] = (short)f2bf(p0.x * dv[0]); s0[1] = (short)f2bf(p0.y * dv[1]);
    s0[2] = (short)f2bf(p0.z * dv[2]); s0[3] = (short)f2bf(p0.w * dv[3]);
    s0[4] = (short)f2bf(p0b.x * dv[4]); s0[5] = (short)f2bf(p0b.y * dv[5]);
    s0[6] = (short)f2bf(p0b.z * dv[6]); s0[7] = (short)f2bf(p0b.w * dv[7]);
    s1[0] = (short)f2bf(p1.x * dv[0]); s1[1] = (short)f2bf(p1.y * dv[1]);
    s1[2] = (short)f2bf(p1.z * dv[2]); s1[3] = (short)f2bf(p1.w * dv[3]);
    s1[4] = (short)f2bf(p1b.x * dv[4]); s1[5] = (short)f2bf(p1b.y * dv[5]);
    s1[6] = (short)f2bf(p1b.z * dv[6]); s1[7] = (short)f2bf(p1b.w * dv[7]);
    *(short8*)&buS[r0 * 136 + ch * 8] = s0;
    *(short8*)&buS[(r0 + 16) * 136 + ch * 8] = s1;
    __syncthreads();
    if (tau < 7) {
      const float* q0 = u0 + (tau + 1) * 320;
      const float* q1 = u1 + (tau + 1) * 320;
      p0 = *(const float4*)q0; p0b = *(const float4*)(q0 + 4);
      p1 = *(const float4*)q1; p1b = *(const float4*)(q1 + 4);
    }
    f32x4 acc[2][2];
#pragma unroll
    for (int mt = 0; mt < 2; mt++)
#pragma unroll
      for (int nt = 0; nt < 2; nt++) acc[mt][nt] = (f32x4){0.f, 0.f, 0.f, 0.f};
    if (tau > 0) {
#pragma unroll
      for (int ks = 0; ks < 4; ks++) {
        const int k0 = ks * 32 + lq * 8;
#pragma unroll
        for (int mt = 0; mt < 2; mt++) {
          short8 a = *(const short8*)&hS[tau & 1][(mt * 16 + lm) * 136 + k0];
          acc[mt][0] = mfma16(a, bfr[0][ks], acc[mt][0]);
          acc[mt][1] = mfma16(a, bfr[1][ks], acc[mt][1]);
        }
      }
    }
#pragma unroll
    for (int mt = 0; mt < 2; mt++)
#pragma unroll
      for (int nt = 0; nt < 2; nt++) {
        const int n = (w * 2 + nt) * 16 + lm;
#pragma unroll
        for (int r = 0; r < 4; r++) {
          const int m = mt * 16 + lq * 4 + r;
          float v = acc[mt][nt][r] + bf2f(buS[m * 136 + n]);
          u16 hv = f2bf(v);
          hS[(tau + 1) & 1][m * 136 + n] = hv;
          lb[((size_t)t * 32 + m) * 128 + n] = hv;
          if (tau == 7 && c < 255) yb[((size_t)(c + 1)) * 4096 + m * 128 + n] = hv;
        }
      }
    __syncthreads();
  }
}

// ---------------- KS carry level: dst[c] = src[c] + src[c-dist] @ A^{8*dist} ----------------
__global__ __launch_bounds__(256) void ksl_k(const u16* __restrict__ src, const u16* __restrict__ Tp,
                                             u16* __restrict__ dst, int dist) {
  const int c = blockIdx.x, tid = threadIdx.x;
  if (c < dist) {
    const uint4* s = (const uint4*)(src + (size_t)c * 4096);
    uint4* d = (uint4*)(dst + (size_t)c * 4096);
    for (int i = tid; i < 512; i += 256) d[i] = s[i];
    return;
  }
  __shared__ __align__(16) u16 inS[32 * 136];
  const int w = tid >> 6, l = tid & 63, lm = l & 15, lq = l >> 4;
  short8 bfr[2][4];
#pragma unroll
  for (int nt = 0; nt < 2; nt++)
#pragma unroll
    for (int ks = 0; ks < 4; ks++) {
      int n = (w * 2 + nt) * 16 + lm, k0 = ks * 32 + lq * 8;
      bfr[nt][ks] = *(const short8*)&Tp[n * 128 + k0];
    }
  for (int i = tid; i < 512; i += 256) {
    int row = i >> 4, chh = i & 15;
    *(uint4*)&inS[row * 136 + chh * 8] = *(const uint4*)&src[(size_t)(c - dist) * 4096 + row * 128 + chh * 8];
  }
  __syncthreads();
  f32x4 acc[2][2];
#pragma unroll
  for (int mt = 0; mt < 2; mt++)
#pragma unroll
    for (int nt = 0; nt < 2; nt++) acc[mt][nt] = (f32x4){0.f, 0.f, 0.f, 0.f};
#pragma unroll
  for (int ks = 0; ks < 4; ks++) {
    const int k0 = ks * 32 + lq * 8;
#pragma unroll
    for (int mt = 0; mt < 2; mt++) {
      short8 a = *(const short8*)&inS[(mt * 16 + lm) * 136 + k0];
      acc[mt][0] = mfma16(a, bfr[0][ks], acc[mt][0]);
      acc[mt][1] = mfma16(a, bfr[1][ks], acc[mt][1]);
    }
  }
#pragma unroll
  for (int mt = 0; mt < 2; mt++)
#pragma unroll
    for (int nt = 0; nt < 2; nt++) {
      const int n = (w * 2 + nt) * 16 + lm;
#pragma unroll
      for (int r = 0; r < 4; r++) {
        const int m = mt * 16 + lq * 4 + r;
        float v = acc[mt][nt][r] + bf2f(src[(size_t)c * 4096 + m * 128 + n]);
        dst[(size_t)c * 4096 + m * 128 + n] = f2bf(v);
      }
    }
}

// ---------------- phase 3: h[c*8+tau] = ins_c @ A^{tau+1} + lb ----------------
__global__ __launch_bounds__(256) void phase3_k(const u16* __restrict__ ins, const u16* __restrict__ powT,
                                                const u16* __restrict__ lb, u16* __restrict__ hb) {
  __shared__ __align__(16) u16 inS[32 * 136];
  const int c = blockIdx.x >> 3, tau = blockIdx.x & 7, t = c * 8 + tau;
  const int tid = threadIdx.x;
  const int w = tid >> 6, l = tid & 63, lm = l & 15, lq = l >> 4;
  const u16* Tj = powT + (size_t)(tau + 1) * 16384;
  short8 bfr[2][4];
#pragma unroll
  for (int nt = 0; nt < 2; nt++)
#pragma unroll
    for (int ks = 0; ks < 4; ks++) {
      int n = (w * 2 + nt) * 16 + lm, k0 = ks * 32 + lq * 8;
      bfr[nt][ks] = *(const short8*)&Tj[n * 128 + k0];
    }
  for (int i = tid; i < 512; i += 256) {
    int row = i >> 4, ch = i & 15;
    *(uint4*)&inS[row * 136 + ch * 8] = *(const uint4*)&ins[(size_t)c * 4096 + row * 128 + ch * 8];
  }
  __syncthreads();
  f32x4 acc[2][2];
#pragma unroll
  for (int mt = 0; mt < 2; mt++)
#pragma unroll
    for (int nt = 0; nt < 2; nt++) acc[mt][nt] = (f32x4){0.f, 0.f, 0.f, 0.f};
#pragma unroll
  for (int ks = 0; ks < 4; ks++) {
    const int k0 = ks * 32 + lq * 8;
#pragma unroll
    for (int mt = 0; mt < 2; mt++) {
      short8 a = *(const short8*)&inS[(mt * 16 + lm) * 136 + k0];
      acc[mt][0] = mfma16(a, bfr[0][ks], acc[mt][0]);
      acc[mt][1] = mfma16(a, bfr[1][ks], acc[mt][1]);
    }
  }
#pragma unroll
  for (int mt = 0; mt < 2; mt++)
#pragma unroll
    for (int nt = 0; nt < 2; nt++) {
      const int n = (w * 2 + nt) * 16 + lm;
#pragma unroll
      for (int r = 0; r < 4; r++) {
        const int m = mt * 16 + lq * 4 + r;
        float v = acc[mt][nt][r] + bf2f(lb[((size_t)t * 32 + m) * 128 + n]);
        hb[((size_t)m * 2048 + t) * 128 + n] = f2bf(v);
      }
    }
}

// ---------------- launcher ----------------
extern "C" void kernel_launch(void* const* d_in, const int* in_sizes, int n_in,
                              void* d_out, int out_size, void* d_ws, size_t ws_size,
                              hipStream_t stream) {
  const float* in  = (const float*)d_in[0];
  const float* ew0 = (const float*)d_in[1];  const float* eb0 = (const float*)d_in[2];
  const float* ew1 = (const float*)d_in[3];  const float* eb1 = (const float*)d_in[4];
  const float* ew2 = (const float*)d_in[5];  const float* eb2 = (const float*)d_in[6];
  const float* gam = (const float*)d_in[7];  const float* bet = (const float*)d_in[8];
  const float* Aw  = (const float*)d_in[9];  const float* Bd  = (const float*)d_in[10];
  const float* dw0 = (const float*)d_in[11]; const float* db0 = (const float*)d_in[12];
  const float* dw1 = (const float*)d_in[13]; const float* db1 = (const float*)d_in[14];
  const float* dw2 = (const float*)d_in[15]; const float* db2 = (const float*)d_in[16];

  char* ws = (char*)d_ws;
  u16*   h0   = (u16*)(ws + OFF_H0);
  u16*   h1   = (u16*)(ws + OFF_H1);
  u16*   zb   = (u16*)(ws + OFF_ZB);
  u16*   hb   = (u16*)(ws + OFF_HB);
  u16*   lbuf = (u16*)(ws + OFF_LB);
  u16*   wt   = (u16*)(ws + OFF_WT);
  float* powR = (float*)(ws + OFF_POWR);
  u16*   powT = (u16*)(ws + OFF_POWT);
  float* st   = (float*)(ws + OFF_ST);
  u16*   yb   = (u16*)(ws + OFF_YB);
  u16*   g1   = (u16*)(ws + OFF_G1);
  u16*   ins  = (u16*)(ws + OFF_INS);
  float* out  = (float*)d_out;

  hipMemsetAsync(ws + OFF_ST, 0, 1024, stream);
  convw_k<<<960, 256, 0, stream>>>(ew0, ew1, ew2, dw0, dw1, dw2, Aw, wt, powR, powT);

  // A powers 1..8 + 16 (fp32 log-doubling)
  pow_round_k<<<4, 256, 0, stream>>>(powR, powT, 1, 0);
  pow_round_k<<<8, 256, 0, stream>>>(powR, powT, 2, 0);
  pow_round_k<<<16, 256, 0, stream>>>(powR, powT, 4, 0);
  pow_round_k<<<4, 256, 0, stream>>>(powR, powT, 8, 7);   // A^16 only

  // encoder (enc1 reads fp32 input directly, strided)
  gemm_k<64, 128, 320, 0, true, true, false><<<dim3(512, 2), 256, 0, stream>>>(in, wt + OW0, eb0, h0, nullptr, 256);
  gemm_k<256, 128, 256, 0, false, true, false><<<dim3(512, 2), 256, 0, stream>>>(h0, wt + OW1, eb1, h1, nullptr, 256);
  gemm_k<256, 128, 256, 0, false, true, false><<<dim3(512, 1), 256, 0, stream>>>(h1, wt + OW2, eb2, zb, nullptr, 128);

  // batchnorm stats + seed state
  stats_k<<<256, 256, 0, stream>>>(zb, st);
  finalize_k<<<1, 128, 0, stream>>>(st, zb, gam, bet, yb);

  // chunked scan: local (C=8, P=256) -> 2 KS levels -> recombine
  phase1_k<<<256, 256, 0, stream>>>(in, Bd, powT, lbuf, yb);
  ksl_k<<<256, 256, 0, stream>>>(yb, powT + (size_t)8 * 16384, g1, 1);
  ksl_k<<<256, 256, 0, stream>>>(g1, powT + (size_t)16 * 16384, ins, 2);
  phase3_k<<<2048, 256, 0, stream>>>(ins, powT, lbuf, hb);

  // decoder
  gemm_k<128, 128, 128, 0, false, true, false><<<dim3(512, 2), 256, 0, stream>>>(hb, wt + OD0, db0, h0, nullptr, 256);
  gemm_k<256, 128, 256, 0, false, true, false><<<dim3(512, 2), 256, 0, stream>>>(h0, wt + OD1, db1, h1, nullptr, 256);
  gemm_k<256, 64, 256, 0, false, false, true><<<dim3(512, 1), 256, 0, stream>>>(h1, wt + OD2, db2, nullptr, out, 64);
}

// Round 5
// 376.811 us; speedup vs baseline: 1.1983x; 1.1983x over previous
//
#include <hip/hip_runtime.h>

#define DI __device__ __forceinline__

typedef __attribute__((ext_vector_type(8))) short short8;
typedef __attribute__((ext_vector_type(4))) float f32x4;
typedef unsigned short u16;
typedef unsigned int u32;

DI u16 f2bf(float f) {
  union { float f; u32 u; } v; v.f = f;
  u32 r = v.u + 0x7FFFu + ((v.u >> 16) & 1u);
  return (u16)(r >> 16);
}
DI float bf2f(u16 h) {
  union { u32 u; float f; } v; v.u = ((u32)h) << 16; return v.f;
}
DI f32x4 mfma16(short8 a, short8 b, f32x4 c) {
  return __builtin_amdgcn_mfma_f32_16x16x32_bf16(a, b, c, 0, 0, 0);
}

// B=32, S=2048, STATE=64, LATENT=128, ENC=256, INPUT_DIM=320, TOK=65536
// scan: C=8, P=256 chunks; carry resolve = 3-term KS (A^8, A^16), trunc ~1e-8.

// ---------------- workspace layout (bytes) ----------------
static const size_t OFF_HB   = 0;                       // 65536*128 bf16 = 16 MB (scan out)
static const size_t OFF_LB   = 16777216;                // 65536*128 bf16 = 16 MB  [t][b][k]
static const size_t OFF_WT   = 33554432;                // 229376 bf16 transposed weights
static const size_t OFF_POWR = 34013184;                // 17*16384 f32 (A^j)
static const size_t OFF_POWT = 35127296;                // 17*16384 bf16 (A^j transposed [n][k])
static const size_t OFF_ST   = 35684352;                // 256 f32 stats
static const size_t OFF_ZB0  = 35685376;                // 32*128 bf16 z[:,0,:] raw
static const size_t OFF_YB   = 35693568;                // 256*32*128 bf16 chunk carries
static const size_t OFF_INS  = 37790720;                // 256*32*128 bf16 resolved carries

#define OW0 0
#define OW1 16384
#define OW2 81920
#define OD0 114688
#define OD1 147456
#define OD2 212992

// ---------------- weight convert: bf16 transposed [n][k]; seed A^1 ----------------
__global__ __launch_bounds__(256) void convw_k(const float* __restrict__ ew0, const float* __restrict__ ew1,
                                               const float* __restrict__ ew2, const float* __restrict__ dw0,
                                               const float* __restrict__ dw1, const float* __restrict__ dw2,
                                               const float* __restrict__ Aw, u16* __restrict__ wt,
                                               float* __restrict__ powR, u16* __restrict__ powT) {
  int idx = blockIdx.x * 256 + threadIdx.x;
  if (idx < 16384) { int n = idx >> 6, k = idx & 63;  wt[OW0 + idx] = f2bf(ew0[k * 256 + n]); return; }
  idx -= 16384;
  if (idx < 65536) { int n = idx >> 8, k = idx & 255; wt[OW1 + idx] = f2bf(ew1[k * 256 + n]); return; }
  idx -= 65536;
  if (idx < 32768) { int n = idx >> 8, k = idx & 255; wt[OW2 + idx] = f2bf(ew2[k * 128 + n]); return; }
  idx -= 32768;
  if (idx < 32768) { int n = idx >> 7, k = idx & 127; wt[OD0 + idx] = f2bf(dw0[k * 256 + n]); return; }
  idx -= 32768;
  if (idx < 65536) { int n = idx >> 8, k = idx & 255; wt[OD1 + idx] = f2bf(dw1[k * 256 + n]); return; }
  idx -= 65536;
  if (idx < 16384) { int n = idx >> 8, k = idx & 255; wt[OD2 + idx] = f2bf(dw2[k * 64 + n]); return; }
  idx -= 16384;
  { int k = idx >> 7, n = idx & 127;
    powR[16384 + idx] = Aw[idx];
    powT[16384 + n * 128 + k] = f2bf(Aw[idx]); }
}

// ---------------- MFMA layer: acc += A_lds[32xK] @ W_glb[K x NTW*16-slice] ----------------
template <int K, int KP, int NTW>
DI void layer(const u16* __restrict__ A, const u16* __restrict__ WT, int n0, int lm, int lq,
              f32x4 (&acc)[2][NTW]) {
  constexpr int KS = K / 32;
  constexpr int H = (KS > 4) ? 2 : 1;
  constexpr int KSH = KS / H;
#pragma unroll
  for (int h = 0; h < H; h++) {
    short8 bfr[NTW][KSH];
#pragma unroll
    for (int nt = 0; nt < NTW; nt++)
#pragma unroll
      for (int ks = 0; ks < KSH; ks++)
        bfr[nt][ks] = *(const short8*)&WT[(size_t)(n0 + nt * 16 + lm) * K + (h * KSH + ks) * 32 + lq * 8];
#pragma unroll
    for (int ks = 0; ks < KSH; ks++) {
      const int k0 = (h * KSH + ks) * 32 + lq * 8;
      short8 a0 = *(const short8*)&A[(0 * 16 + lm) * KP + k0];
      short8 a1 = *(const short8*)&A[(1 * 16 + lm) * KP + k0];
#pragma unroll
      for (int nt = 0; nt < NTW; nt++) {
        acc[0][nt] = mfma16(a0, bfr[nt][ks], acc[0][nt]);
        acc[1][nt] = mfma16(a1, bfr[nt][ks], acc[1][nt]);
      }
    }
  }
}

// ---------------- fused encoder: x(fp32,strided) -> relu MLP x3 -> stats + z[:,0,:] only ----------------
__global__ __launch_bounds__(256) void enc_k(const float* __restrict__ in, const u16* __restrict__ wt,
                                             const float* __restrict__ b0, const float* __restrict__ b1,
                                             const float* __restrict__ b2, float* __restrict__ st,
                                             u16* __restrict__ zb0) {
  __shared__ __align__(16) u16 bufA[32 * 264];
  __shared__ __align__(16) u16 bufB[32 * 264];
  __shared__ float sSum[128], sSq[128];
  const int tid = threadIdx.x, w = tid >> 6, l = tid & 63, lm = l & 15, lq = l >> 4;
  const int m0 = blockIdx.x * 32;
  // stage x: 32 rows x 64 cols fp32 -> bf16, stride 72
#pragma unroll
  for (int it = 0; it < 2; it++) {
    int idx = tid + it * 256;
    int row = idx >> 4, c4 = idx & 15;
    float4 f = *(const float4*)&in[(size_t)(m0 + row) * 320 + c4 * 4];
    u32 lo = (u32)f2bf(f.x) | ((u32)f2bf(f.y) << 16);
    u32 hi = (u32)f2bf(f.z) | ((u32)f2bf(f.w) << 16);
    *(uint2*)&bufA[row * 72 + c4 * 4] = make_uint2(lo, hi);
  }
  __syncthreads();
  // L0: 64 -> 256
  {
    f32x4 acc[2][4];
#pragma unroll
    for (int i = 0; i < 2; i++)
#pragma unroll
      for (int j = 0; j < 4; j++) acc[i][j] = (f32x4){0.f, 0.f, 0.f, 0.f};
    layer<64, 72, 4>(bufA, wt + OW0, w * 64, lm, lq, acc);
#pragma unroll
    for (int nt = 0; nt < 4; nt++) {
      const int n = w * 64 + nt * 16 + lm;
      const float bv = b0[n];
#pragma unroll
      for (int mt = 0; mt < 2; mt++)
#pragma unroll
        for (int r = 0; r < 4; r++) {
          const int m = mt * 16 + lq * 4 + r;
          bufB[m * 264 + n] = f2bf(fmaxf(acc[mt][nt][r] + bv, 0.f));
        }
    }
  }
  __syncthreads();
  // L1: 256 -> 256
  {
    f32x4 acc[2][4];
#pragma unroll
    for (int i = 0; i < 2; i++)
#pragma unroll
      for (int j = 0; j < 4; j++) acc[i][j] = (f32x4){0.f, 0.f, 0.f, 0.f};
    layer<256, 264, 4>(bufB, wt + OW1, w * 64, lm, lq, acc);
#pragma unroll
    for (int nt = 0; nt < 4; nt++) {
      const int n = w * 64 + nt * 16 + lm;
      const float bv = b1[n];
#pragma unroll
      for (int mt = 0; mt < 2; mt++)
#pragma unroll
        for (int r = 0; r < 4; r++) {
          const int m = mt * 16 + lq * 4 + r;
          bufA[m * 264 + n] = f2bf(fmaxf(acc[mt][nt][r] + bv, 0.f));
        }
    }
  }
  __syncthreads();
  // L2: 256 -> 128, stats + t=0 slice only
  {
    f32x4 acc[2][2];
#pragma unroll
    for (int i = 0; i < 2; i++)
#pragma unroll
      for (int j = 0; j < 2; j++) acc[i][j] = (f32x4){0.f, 0.f, 0.f, 0.f};
    layer<256, 264, 2>(bufA, wt + OW2, w * 32, lm, lq, acc);
    const bool t0blk = ((m0 & 2047) == 0);
#pragma unroll
    for (int nt = 0; nt < 2; nt++) {
      const int n = w * 32 + nt * 16 + lm;
      const float bv = b2[n];
      float sl = 0.f, sq = 0.f, r0v = 0.f;
#pragma unroll
      for (int mt = 0; mt < 2; mt++)
#pragma unroll
        for (int r = 0; r < 4; r++) {
          float v = fmaxf(acc[mt][nt][r] + bv, 0.f);
          sl += v; sq += v * v;
          if (mt == 0 && r == 0) r0v = v;
        }
      sl += __shfl_xor(sl, 16); sl += __shfl_xor(sl, 32);
      sq += __shfl_xor(sq, 16); sq += __shfl_xor(sq, 32);
      if (lq == 0) {
        sSum[n] = sl; sSq[n] = sq;
        if (t0blk) zb0[(m0 >> 11) * 128 + n] = f2bf(r0v);
      }
    }
  }
  __syncthreads();
  if (tid < 128) atomicAdd(&st[tid], sSum[tid]);
  else atomicAdd(&st[tid], sSq[tid - 128]);
}

// ---------------- fused decoder: hb(bf16) -> relu MLP x2 -> fp32 out ----------------
__global__ __launch_bounds__(256) void dec_k(const u16* __restrict__ hb, const u16* __restrict__ wt,
                                             const float* __restrict__ b0, const float* __restrict__ b1,
                                             const float* __restrict__ b2, float* __restrict__ out) {
  __shared__ __align__(16) u16 bufA[32 * 264];
  __shared__ __align__(16) u16 bufB[32 * 264];
  const int tid = threadIdx.x, w = tid >> 6, l = tid & 63, lm = l & 15, lq = l >> 4;
  const int m0 = blockIdx.x * 32;
  // stage hb: 32 rows x 128 bf16, stride 136  (512 uint4 total — FULL tile)
  for (int i = tid; i < 512; i += 256) {
    int row = i >> 4, c8 = i & 15;
    *(uint4*)&bufA[row * 136 + c8 * 8] = *(const uint4*)&hb[(size_t)(m0 + row) * 128 + c8 * 8];
  }
  __syncthreads();
  // L0: 128 -> 256
  {
    f32x4 acc[2][4];
#pragma unroll
    for (int i = 0; i < 2; i++)
#pragma unroll
      for (int j = 0; j < 4; j++) acc[i][j] = (f32x4){0.f, 0.f, 0.f, 0.f};
    layer<128, 136, 4>(bufA, wt + OD0, w * 64, lm, lq, acc);
#pragma unroll
    for (int nt = 0; nt < 4; nt++) {
      const int n = w * 64 + nt * 16 + lm;
      const float bv = b0[n];
#pragma unroll
      for (int mt = 0; mt < 2; mt++)
#pragma unroll
        for (int r = 0; r < 4; r++) {
          const int m = mt * 16 + lq * 4 + r;
          bufB[m * 264 + n] = f2bf(fmaxf(acc[mt][nt][r] + bv, 0.f));
        }
    }
  }
  __syncthreads();
  // L1: 256 -> 256
  {
    f32x4 acc[2][4];
#pragma unroll
    for (int i = 0; i < 2; i++)
#pragma unroll
      for (int j = 0; j < 4; j++) acc[i][j] = (f32x4){0.f, 0.f, 0.f, 0.f};
    layer<256, 264, 4>(bufB, wt + OD1, w * 64, lm, lq, acc);
#pragma unroll
    for (int nt = 0; nt < 4; nt++) {
      const int n = w * 64 + nt * 16 + lm;
      const float bv = b1[n];
#pragma unroll
      for (int mt = 0; mt < 2; mt++)
#pragma unroll
        for (int r = 0; r < 4; r++) {
          const int m = mt * 16 + lq * 4 + r;
          bufA[m * 264 + n] = f2bf(fmaxf(acc[mt][nt][r] + bv, 0.f));
        }
    }
  }
  __syncthreads();
  // L2: 256 -> 64, fp32 out
  {
    f32x4 acc[2][1];
    acc[0][0] = (f32x4){0.f, 0.f, 0.f, 0.f};
    acc[1][0] = (f32x4){0.f, 0.f, 0.f, 0.f};
    layer<256, 264, 1>(bufA, wt + OD2, w * 16, lm, lq, acc);
    const int n = w * 16 + lm;
    const float bv = b2[n];
#pragma unroll
    for (int mt = 0; mt < 2; mt++)
#pragma unroll
      for (int r = 0; r < 4; r++) {
        const int m = mt * 16 + lq * 4 + r;
        out[(size_t)(m0 + m) * 64 + n] = acc[mt][0][r] + bv;
      }
  }
}

// ---------------- finalize: mean/var from stats -> normalize z[:,0,:] -> yb[0] seed ----------------
__global__ __launch_bounds__(128) void finalize_k(const float* __restrict__ st, const u16* __restrict__ zb0,
                                                  const float* __restrict__ gam, const float* __restrict__ bet,
                                                  u16* __restrict__ yb) {
  const int ch = threadIdx.x;
  const float mean = st[ch] * (1.f / 65536.f);
  const float var = st[128 + ch] * (1.f / 65536.f) - mean * mean;
  const float sc = rsqrtf(var + 1e-5f) * gam[ch];
  const float sh = bet[ch] - mean * sc;
  for (int b = 0; b < 32; b++) {
    float z = bf2f(zb0[b * 128 + ch]);
    yb[b * 128 + ch] = f2bf(z * sc + sh);
  }
}

// ---------------- matrix powers (fp32): A^{p+mi+1} = A^p * A^{mi+1} ----------------
__global__ __launch_bounds__(256) void pow_round_k(float* __restrict__ powR, u16* __restrict__ powT,
                                                   int p, int mi_base) {
  const int mi = mi_base + (blockIdx.x >> 2), nc = blockIdx.x & 3;
  const float* Rp = powR + (size_t)p * 16384;
  const float* Rm = powR + (size_t)(mi + 1) * 16384;
  float* Ro = powR + (size_t)(p + mi + 1) * 16384;
  u16* To = powT + (size_t)(p + mi + 1) * 16384;
  __shared__ __align__(16) float RpS[128 * 132];
  __shared__ __align__(16) float RmS[128 * 36];
  const int tid = threadIdx.x;
  for (int i = tid; i < 4096; i += 256) {
    int r = i >> 5, c4 = i & 31;
    *(float4*)&RpS[r * 132 + c4 * 4] = *(const float4*)&Rp[r * 128 + c4 * 4];
  }
  for (int i = tid; i < 1024; i += 256) {
    int r = i >> 3, c4 = i & 7;
    *(float4*)&RmS[r * 36 + c4 * 4] = *(const float4*)&Rm[r * 128 + nc * 32 + c4 * 4];
  }
  __syncthreads();
  const int tc = tid & 7, tr = tid >> 3;
  float acc[4][4];
#pragma unroll
  for (int i = 0; i < 4; i++)
#pragma unroll
    for (int j = 0; j < 4; j++) acc[i][j] = 0.f;
  for (int kk = 0; kk < 128; kk++) {
    const float4 bv = *(const float4*)&RmS[kk * 36 + tc * 4];
#pragma unroll
    for (int i = 0; i < 4; i++) {
      const float av = RpS[(tr * 4 + i) * 132 + kk];
      acc[i][0] += av * bv.x; acc[i][1] += av * bv.y;
      acc[i][2] += av * bv.z; acc[i][3] += av * bv.w;
    }
  }
#pragma unroll
  for (int i = 0; i < 4; i++)
#pragma unroll
    for (int j = 0; j < 4; j++) {
      const int row = tr * 4 + i, col = nc * 32 + tc * 4 + j;
      Ro[row * 128 + col] = acc[i][j];
      To[col * 128 + row] = f2bf(acc[i][j]);
    }
}

// ---------------- phase 1: local scans, 256 chunks x 8 steps, bu on the fly ----------------
__global__ __launch_bounds__(256) void phase1_k(const float* __restrict__ in, const float* __restrict__ Bd,
                                                const u16* __restrict__ powT, u16* __restrict__ lb,
                                                u16* __restrict__ yb) {
  __shared__ __align__(16) u16 hS[2][32 * 136];
  __shared__ __align__(16) u16 buS[32 * 136];
  const int tid = threadIdx.x, c = blockIdx.x;
  const int w = tid >> 6, l = tid & 63, lm = l & 15, lq = l >> 4;
  const u16* T1 = powT + 16384;  // A^T
  short8 bfr[2][4];
#pragma unroll
  for (int nt = 0; nt < 2; nt++)
#pragma unroll
    for (int ks = 0; ks < 4; ks++) {
      int n = (w * 2 + nt) * 16 + lm, k0 = ks * 32 + lq * 8;
      bfr[nt][ks] = *(const short8*)&T1[n * 128 + k0];
    }
  const int r0 = tid >> 4, ch = tid & 15;
  float dv[8];
#pragma unroll
  for (int j = 0; j < 8; j++) {
    float d = Bd[ch * 8 + j];
    dv[j] = fminf(0.95f, fmaxf(-0.95f, d));
  }
  const float* u0 = in + (size_t)r0 * 2048 * 320 + (size_t)(c * 8) * 320 + 192 + ch * 8;
  const float* u1 = in + (size_t)(r0 + 16) * 2048 * 320 + (size_t)(c * 8) * 320 + 192 + ch * 8;
  float4 p0 = *(const float4*)u0, p0b = *(const float4*)(u0 + 4);
  float4 p1 = *(const float4*)u1, p1b = *(const float4*)(u1 + 4);
  for (int tau = 0; tau < 8; tau++) {
    const int t = c * 8 + tau;
    short8 s0, s1;
    s0[0] = (short)f2bf(p0.x * dv[0]); s0[1] = (short)f2bf(p0.y * dv[1]);
    s0[2] = (short)f2bf(p0.z * dv[2]); s0[3] = (short)f2bf(p0.w * dv[3]);
    s0[4] = (short)f2bf(p0b.x * dv[4]); s0[5] = (short)f2bf(p0b.y * dv[5]);
    s0[6] = (short)f2bf(p0b.z * dv[6]); s0[7] = (short)f2bf(p0b.w * dv[7]);
    s1[0] = (short)f2bf(p1.x * dv[0]); s1[1] = (short)f2bf(p1.y * dv[1]);
    s1[2] = (short)f2bf(p1.z * dv[2]); s1[3] = (short)f2bf(p1.w * dv[3]);
    s1[4] = (short)f2bf(p1b.x * dv[4]); s1[5] = (short)f2bf(p1b.y * dv[5]);
    s1[6] = (short)f2bf(p1b.z * dv[6]); s1[7] = (short)f2bf(p1b.w * dv[7]);
    *(short8*)&buS[r0 * 136 + ch * 8] = s0;
    *(short8*)&buS[(r0 + 16) * 136 + ch * 8] = s1;
    __syncthreads();
    if (tau < 7) {
      const float* q0 = u0 + (tau + 1) * 320;
      const float* q1 = u1 + (tau + 1) * 320;
      p0 = *(const float4*)q0; p0b = *(const float4*)(q0 + 4);
      p1 = *(const float4*)q1; p1b = *(const float4*)(q1 + 4);
    }
    f32x4 acc[2][2];
#pragma unroll
    for (int mt = 0; mt < 2; mt++)
#pragma unroll
      for (int nt = 0; nt < 2; nt++) acc[mt][nt] = (f32x4){0.f, 0.f, 0.f, 0.f};
    if (tau > 0) {
#pragma unroll
      for (int ks = 0; ks < 4; ks++) {
        const int k0 = ks * 32 + lq * 8;
#pragma unroll
        for (int mt = 0; mt < 2; mt++) {
          short8 a = *(const short8*)&hS[tau & 1][(mt * 16 + lm) * 136 + k0];
          acc[mt][0] = mfma16(a, bfr[0][ks], acc[mt][0]);
          acc[mt][1] = mfma16(a, bfr[1][ks], acc[mt][1]);
        }
      }
    }
#pragma unroll
    for (int mt = 0; mt < 2; mt++)
#pragma unroll
      for (int nt = 0; nt < 2; nt++) {
        const int n = (w * 2 + nt) * 16 + lm;
#pragma unroll
        for (int r = 0; r < 4; r++) {
          const int m = mt * 16 + lq * 4 + r;
          float v = acc[mt][nt][r] + bf2f(buS[m * 136 + n]);
          u16 hv = f2bf(v);
          hS[(tau + 1) & 1][m * 136 + n] = hv;
          lb[((size_t)t * 32 + m) * 128 + n] = hv;
          if (tau == 7 && c < 255) yb[((size_t)(c + 1)) * 4096 + m * 128 + n] = hv;
        }
      }
    __syncthreads();
  }
}

// ---------------- fused 3-term carry resolve:
// ins[c] = y[c] + y[c-1]A^8 + (y[c-2] + y[c-3]A^8)A^16   (trunc >= A^32 ~ 1e-8)
__global__ __launch_bounds__(256) void kslf_k(const u16* __restrict__ yb, const u16* __restrict__ powT,
                                              u16* __restrict__ ins) {
  const int c = blockIdx.x, tid = threadIdx.x;
  if (c == 0) {
    for (int i = tid; i < 512; i += 256) ((uint4*)ins)[i] = ((const uint4*)yb)[i];
    return;
  }
  __shared__ __align__(16) u16 sA[32 * 136];
  __shared__ __align__(16) u16 sW[32 * 136];
  const int w = tid >> 6, l = tid & 63, lm = l & 15, lq = l >> 4;
  const u16* A8 = powT + (size_t)8 * 16384;
  short8 f8[2][4];
#pragma unroll
  for (int nt = 0; nt < 2; nt++)
#pragma unroll
    for (int ks = 0; ks < 4; ks++)
      f8[nt][ks] = *(const short8*)&A8[((w * 2 + nt) * 16 + lm) * 128 + ks * 32 + lq * 8];
  const bool havew = (c >= 2);
  if (c >= 3) {
    for (int i = tid; i < 512; i += 256) {
      int row = i >> 4, chh = i & 15;
      *(uint4*)&sA[row * 136 + chh * 8] = *(const uint4*)&yb[(size_t)(c - 3) * 4096 + row * 128 + chh * 8];
    }
    __syncthreads();
    f32x4 accw[2][2];
#pragma unroll
    for (int mt = 0; mt < 2; mt++)
#pragma unroll
      for (int nt = 0; nt < 2; nt++)
#pragma unroll
        for (int r = 0; r < 4; r++)
          accw[mt][nt][r] = bf2f(yb[(size_t)(c - 2) * 4096 + (mt * 16 + lq * 4 + r) * 128 + (w * 2 + nt) * 16 + lm]);
#pragma unroll
    for (int ks = 0; ks < 4; ks++) {
      const int k0 = ks * 32 + lq * 8;
#pragma unroll
      for (int mt = 0; mt < 2; mt++) {
        short8 a = *(const short8*)&sA[(mt * 16 + lm) * 136 + k0];
        accw[mt][0] = mfma16(a, f8[0][ks], accw[mt][0]);
        accw[mt][1] = mfma16(a, f8[1][ks], accw[mt][1]);
      }
    }
#pragma unroll
    for (int mt = 0; mt < 2; mt++)
#pragma unroll
      for (int nt = 0; nt < 2; nt++)
#pragma unroll
        for (int r = 0; r < 4; r++)
          sW[(mt * 16 + lq * 4 + r) * 136 + (w * 2 + nt) * 16 + lm] = f2bf(accw[mt][nt][r]);
  } else if (c == 2) {
    for (int i = tid; i < 512; i += 256) {
      int row = i >> 4, chh = i & 15;
      *(uint4*)&sW[row * 136 + chh * 8] = *(const uint4*)&yb[row * 128 + chh * 8];  // y[0]
    }
  }
  __syncthreads();
  // stage y[c-1]
  for (int i = tid; i < 512; i += 256) {
    int row = i >> 4, chh = i & 15;
    *(uint4*)&sA[row * 136 + chh * 8] = *(const uint4*)&yb[(size_t)(c - 1) * 4096 + row * 128 + chh * 8];
  }
  __syncthreads();
  f32x4 acc[2][2];
#pragma unroll
  for (int mt = 0; mt < 2; mt++)
#pragma unroll
    for (int nt = 0; nt < 2; nt++)
#pragma unroll
      for (int r = 0; r < 4; r++)
        acc[mt][nt][r] = bf2f(yb[(size_t)c * 4096 + (mt * 16 + lq * 4 + r) * 128 + (w * 2 + nt) * 16 + lm]);
#pragma unroll
  for (int ks = 0; ks < 4; ks++) {
    const int k0 = ks * 32 + lq * 8;
#pragma unroll
    for (int mt = 0; mt < 2; mt++) {
      short8 a = *(const short8*)&sA[(mt * 16 + lm) * 136 + k0];
      acc[mt][0] = mfma16(a, f8[0][ks], acc[mt][0]);
      acc[mt][1] = mfma16(a, f8[1][ks], acc[mt][1]);
    }
  }
  if (havew) {
    const u16* A16 = powT + (size_t)16 * 16384;
    short8 f16a[2][4];
#pragma unroll
    for (int nt = 0; nt < 2; nt++)
#pragma unroll
      for (int ks = 0; ks < 4; ks++)
        f16a[nt][ks] = *(const short8*)&A16[((w * 2 + nt) * 16 + lm) * 128 + ks * 32 + lq * 8];
#pragma unroll
    for (int ks = 0; ks < 4; ks++) {
      const int k0 = ks * 32 + lq * 8;
#pragma unroll
      for (int mt = 0; mt < 2; mt++) {
        short8 a = *(const short8*)&sW[(mt * 16 + lm) * 136 + k0];
        acc[mt][0] = mfma16(a, f16a[0][ks], acc[mt][0]);
        acc[mt][1] = mfma16(a, f16a[1][ks], acc[mt][1]);
      }
    }
  }
#pragma unroll
  for (int mt = 0; mt < 2; mt++)
#pragma unroll
    for (int nt = 0; nt < 2; nt++)
#pragma unroll
      for (int r = 0; r < 4; r++)
        ins[(size_t)c * 4096 + (mt * 16 + lq * 4 + r) * 128 + (w * 2 + nt) * 16 + lm] = f2bf(acc[mt][nt][r]);
}

// ---------------- phase 3: h[c*8+tau] = ins_c @ A^{tau+1} + lb ----------------
__global__ __launch_bounds__(256) void phase3_k(const u16* __restrict__ ins, const u16* __restrict__ powT,
                                                const u16* __restrict__ lb, u16* __restrict__ hb) {
  __shared__ __align__(16) u16 inS[32 * 136];
  const int c = blockIdx.x >> 3, tau = blockIdx.x & 7, t = c * 8 + tau;
  const int tid = threadIdx.x;
  const int w = tid >> 6, l = tid & 63, lm = l & 15, lq = l >> 4;
  const u16* Tj = powT + (size_t)(tau + 1) * 16384;
  short8 bfr[2][4];
#pragma unroll
  for (int nt = 0; nt < 2; nt++)
#pragma unroll
    for (int ks = 0; ks < 4; ks++) {
      int n = (w * 2 + nt) * 16 + lm, k0 = ks * 32 + lq * 8;
      bfr[nt][ks] = *(const short8*)&Tj[n * 128 + k0];
    }
  for (int i = tid; i < 512; i += 256) {
    int row = i >> 4, ch = i & 15;
    *(uint4*)&inS[row * 136 + ch * 8] = *(const uint4*)&ins[(size_t)c * 4096 + row * 128 + ch * 8];
  }
  __syncthreads();
  f32x4 acc[2][2];
#pragma unroll
  for (int mt = 0; mt < 2; mt++)
#pragma unroll
    for (int nt = 0; nt < 2; nt++) acc[mt][nt] = (f32x4){0.f, 0.f, 0.f, 0.f};
#pragma unroll
  for (int ks = 0; ks < 4; ks++) {
    const int k0 = ks * 32 + lq * 8;
#pragma unroll
    for (int mt = 0; mt < 2; mt++) {
      short8 a = *(const short8*)&inS[(mt * 16 + lm) * 136 + k0];
      acc[mt][0] = mfma16(a, bfr[0][ks], acc[mt][0]);
      acc[mt][1] = mfma16(a, bfr[1][ks], acc[mt][1]);
    }
  }
#pragma unroll
  for (int mt = 0; mt < 2; mt++)
#pragma unroll
    for (int nt = 0; nt < 2; nt++) {
      const int n = (w * 2 + nt) * 16 + lm;
#pragma unroll
      for (int r = 0; r < 4; r++) {
        const int m = mt * 16 + lq * 4 + r;
        float v = acc[mt][nt][r] + bf2f(lb[((size_t)t * 32 + m) * 128 + n]);
        hb[((size_t)m * 2048 + t) * 128 + n] = f2bf(v);
      }
    }
}

// ---------------- launcher ----------------
extern "C" void kernel_launch(void* const* d_in, const int* in_sizes, int n_in,
                              void* d_out, int out_size, void* d_ws, size_t ws_size,
                              hipStream_t stream) {
  const float* in  = (const float*)d_in[0];
  const float* ew0 = (const float*)d_in[1];  const float* eb0 = (const float*)d_in[2];
  const float* ew1 = (const float*)d_in[3];  const float* eb1 = (const float*)d_in[4];
  const float* ew2 = (const float*)d_in[5];  const float* eb2 = (const float*)d_in[6];
  const float* gam = (const float*)d_in[7];  const float* bet = (const float*)d_in[8];
  const float* Aw  = (const float*)d_in[9];  const float* Bd  = (const float*)d_in[10];
  const float* dw0 = (const float*)d_in[11]; const float* db0 = (const float*)d_in[12];
  const float* dw1 = (const float*)d_in[13]; const float* db1 = (const float*)d_in[14];
  const float* dw2 = (const float*)d_in[15]; const float* db2 = (const float*)d_in[16];

  char* ws = (char*)d_ws;
  u16*   hb   = (u16*)(ws + OFF_HB);
  u16*   lbuf = (u16*)(ws + OFF_LB);
  u16*   wt   = (u16*)(ws + OFF_WT);
  float* powR = (float*)(ws + OFF_POWR);
  u16*   powT = (u16*)(ws + OFF_POWT);
  float* st   = (float*)(ws + OFF_ST);
  u16*   zb0  = (u16*)(ws + OFF_ZB0);
  u16*   yb   = (u16*)(ws + OFF_YB);
  u16*   ins  = (u16*)(ws + OFF_INS);
  float* out  = (float*)d_out;

  hipMemsetAsync(ws + OFF_ST, 0, 1024, stream);
  convw_k<<<960, 256, 0, stream>>>(ew0, ew1, ew2, dw0, dw1, dw2, Aw, wt, powR, powT);

  // A powers: 1..8 and 16
  pow_round_k<<<4, 256, 0, stream>>>(powR, powT, 1, 0);
  pow_round_k<<<8, 256, 0, stream>>>(powR, powT, 2, 0);
  pow_round_k<<<16, 256, 0, stream>>>(powR, powT, 4, 0);
  pow_round_k<<<4, 256, 0, stream>>>(powR, powT, 8, 7);   // A^16

  // local scans (independent of encoder)
  phase1_k<<<256, 256, 0, stream>>>(in, Bd, powT, lbuf, yb);

  // fused encoder (stats + z[:,0,:] only)
  enc_k<<<2048, 256, 0, stream>>>(in, wt, eb0, eb1, eb2, st, zb0);
  finalize_k<<<1, 128, 0, stream>>>(st, zb0, gam, bet, yb);

  // carry resolve + recombine
  kslf_k<<<256, 256, 0, stream>>>(yb, powT, ins);
  phase3_k<<<2048, 256, 0, stream>>>(ins, powT, lbuf, hb);

  // fused decoder
  dec_k<<<2048, 256, 0, stream>>>(hb, wt, db0, db1, db2, out);
}

// Round 6
// 308.034 us; speedup vs baseline: 1.4658x; 1.2233x over previous
//
#include <hip/hip_runtime.h>

#define DI __device__ __forceinline__

typedef __attribute__((ext_vector_type(8))) short short8;
typedef __attribute__((ext_vector_type(4))) float f32x4;
typedef unsigned short u16;
typedef unsigned int u32;

DI u16 f2bf(float f) {
  union { float f; u32 u; } v; v.f = f;
  u32 r = v.u + 0x7FFFu + ((v.u >> 16) & 1u);
  return (u16)(r >> 16);
}
DI float bf2f(u16 h) {
  union { u32 u; float f; } v; v.u = ((u32)h) << 16; return v.f;
}
DI f32x4 mfma16(short8 a, short8 b, f32x4 c) {
  return __builtin_amdgcn_mfma_f32_16x16x32_bf16(a, b, c, 0, 0, 0);
}

// B=32, S=2048, STATE=64, LATENT=128, ENC=256, INPUT_DIM=320, TOK=65536
// scan: C=8, P=256 chunks; carry resolve = 3-term KS (A^8, A^16), trunc ~1e-8.

// ---------------- workspace layout (bytes) ----------------
static const size_t OFF_HB   = 0;                       // 65536*128 bf16 = 16 MB (scan out)
static const size_t OFF_LB   = 16777216;                // 65536*128 bf16 = 16 MB  [t][b][k]
static const size_t OFF_WT   = 33554432;                // 229376 bf16 transposed weights
static const size_t OFF_POWR = 34013184;                // 17*16384 f32 (A^j)
static const size_t OFF_POWT = 35127296;                // 17*16384 bf16 (A^j transposed [n][k])
static const size_t OFF_ST   = 35684352;                // 8 replicas x 256 f32 stats = 8 KB
static const size_t OFF_ZB0  = 35692544;                // 32*128 bf16 z[:,0,:] raw
static const size_t OFF_YB   = 35700736;                // 256*32*128 bf16 chunk carries
static const size_t OFF_INS  = 37797888;                // 256*32*128 bf16 resolved carries

#define OW0 0
#define OW1 16384
#define OW2 81920
#define OD0 114688
#define OD1 147456
#define OD2 212992

// ---------------- weight convert: bf16 transposed [n][k]; seed A^1 ----------------
__global__ __launch_bounds__(256) void convw_k(const float* __restrict__ ew0, const float* __restrict__ ew1,
                                               const float* __restrict__ ew2, const float* __restrict__ dw0,
                                               const float* __restrict__ dw1, const float* __restrict__ dw2,
                                               const float* __restrict__ Aw, u16* __restrict__ wt,
                                               float* __restrict__ powR, u16* __restrict__ powT) {
  int idx = blockIdx.x * 256 + threadIdx.x;
  if (idx < 16384) { int n = idx >> 6, k = idx & 63;  wt[OW0 + idx] = f2bf(ew0[k * 256 + n]); return; }
  idx -= 16384;
  if (idx < 65536) { int n = idx >> 8, k = idx & 255; wt[OW1 + idx] = f2bf(ew1[k * 256 + n]); return; }
  idx -= 65536;
  if (idx < 32768) { int n = idx >> 8, k = idx & 255; wt[OW2 + idx] = f2bf(ew2[k * 128 + n]); return; }
  idx -= 32768;
  if (idx < 32768) { int n = idx >> 7, k = idx & 127; wt[OD0 + idx] = f2bf(dw0[k * 256 + n]); return; }
  idx -= 32768;
  if (idx < 65536) { int n = idx >> 8, k = idx & 255; wt[OD1 + idx] = f2bf(dw1[k * 256 + n]); return; }
  idx -= 65536;
  if (idx < 16384) { int n = idx >> 8, k = idx & 255; wt[OD2 + idx] = f2bf(dw2[k * 64 + n]); return; }
  idx -= 16384;
  { int k = idx >> 7, n = idx & 127;
    powR[16384 + idx] = Aw[idx];
    powT[16384 + n * 128 + k] = f2bf(Aw[idx]); }
}

// ---------------- MFMA layer: acc[MT][NTW] += A_lds[MT*16 x K] @ W_glb slice ----------------
// Weight fragments batched into registers per K-half -> single vmcnt wait.
template <int K, int KP, int NTW, int MT>
DI void layer(const u16* __restrict__ A, const u16* __restrict__ WT, int n0, int lm, int lq,
              f32x4 (&acc)[MT][NTW]) {
  constexpr int KS = K / 32;
  constexpr int H = (KS > 4) ? 2 : 1;
  constexpr int KSH = KS / H;
#pragma unroll
  for (int h = 0; h < H; h++) {
    short8 bfr[NTW][KSH];
#pragma unroll
    for (int nt = 0; nt < NTW; nt++)
#pragma unroll
      for (int ks = 0; ks < KSH; ks++)
        bfr[nt][ks] = *(const short8*)&WT[(size_t)(n0 + nt * 16 + lm) * K + (h * KSH + ks) * 32 + lq * 8];
#pragma unroll
    for (int ks = 0; ks < KSH; ks++) {
      const int k0 = (h * KSH + ks) * 32 + lq * 8;
      short8 a[MT];
#pragma unroll
      for (int mt = 0; mt < MT; mt++)
        a[mt] = *(const short8*)&A[(mt * 16 + lm) * KP + k0];
#pragma unroll
      for (int nt = 0; nt < NTW; nt++)
#pragma unroll
        for (int mt = 0; mt < MT; mt++)
          acc[mt][nt] = mfma16(a[mt], bfr[nt][ks], acc[mt][nt]);
    }
  }
}

// ---------------- fused encoder: 64-row tile; x -> relu MLP x3 -> stats + z[:,0,:] ----------------
__global__ __launch_bounds__(256, 2) void enc_k(const float* __restrict__ in, const u16* __restrict__ wt,
                                                const float* __restrict__ b0, const float* __restrict__ b1,
                                                const float* __restrict__ b2, float* __restrict__ st,
                                                u16* __restrict__ zb0) {
  __shared__ __align__(16) u16 bufA[64 * 264];
  __shared__ __align__(16) u16 bufB[64 * 264];
  __shared__ float sSum[128], sSq[128];
  const int tid = threadIdx.x, w = tid >> 6, l = tid & 63, lm = l & 15, lq = l >> 4;
  const int m0 = blockIdx.x * 64;
  // stage x: 64 rows x 64 cols fp32 -> bf16, stride 72
  for (int i = tid; i < 1024; i += 256) {
    int row = i >> 4, c4 = i & 15;
    float4 f = *(const float4*)&in[(size_t)(m0 + row) * 320 + c4 * 4];
    u32 lo = (u32)f2bf(f.x) | ((u32)f2bf(f.y) << 16);
    u32 hi = (u32)f2bf(f.z) | ((u32)f2bf(f.w) << 16);
    *(uint2*)&bufA[row * 72 + c4 * 4] = make_uint2(lo, hi);
  }
  __syncthreads();
  // L0: 64 -> 256
  {
    f32x4 acc[4][4];
#pragma unroll
    for (int i = 0; i < 4; i++)
#pragma unroll
      for (int j = 0; j < 4; j++) acc[i][j] = (f32x4){0.f, 0.f, 0.f, 0.f};
    layer<64, 72, 4, 4>(bufA, wt + OW0, w * 64, lm, lq, acc);
    __syncthreads();
#pragma unroll
    for (int nt = 0; nt < 4; nt++) {
      const int n = w * 64 + nt * 16 + lm;
      const float bv = b0[n];
#pragma unroll
      for (int mt = 0; mt < 4; mt++)
#pragma unroll
        for (int r = 0; r < 4; r++) {
          const int m = mt * 16 + lq * 4 + r;
          bufB[m * 264 + n] = f2bf(fmaxf(acc[mt][nt][r] + bv, 0.f));
        }
    }
  }
  __syncthreads();
  // L1: 256 -> 256
  {
    f32x4 acc[4][4];
#pragma unroll
    for (int i = 0; i < 4; i++)
#pragma unroll
      for (int j = 0; j < 4; j++) acc[i][j] = (f32x4){0.f, 0.f, 0.f, 0.f};
    layer<256, 264, 4, 4>(bufB, wt + OW1, w * 64, lm, lq, acc);
    __syncthreads();
#pragma unroll
    for (int nt = 0; nt < 4; nt++) {
      const int n = w * 64 + nt * 16 + lm;
      const float bv = b1[n];
#pragma unroll
      for (int mt = 0; mt < 4; mt++)
#pragma unroll
        for (int r = 0; r < 4; r++) {
          const int m = mt * 16 + lq * 4 + r;
          bufA[m * 264 + n] = f2bf(fmaxf(acc[mt][nt][r] + bv, 0.f));
        }
    }
  }
  __syncthreads();
  // L2: 256 -> 128, stats + t=0 slice only
  {
    f32x4 acc[4][2];
#pragma unroll
    for (int i = 0; i < 4; i++)
#pragma unroll
      for (int j = 0; j < 2; j++) acc[i][j] = (f32x4){0.f, 0.f, 0.f, 0.f};
    layer<256, 264, 2, 4>(bufA, wt + OW2, w * 32, lm, lq, acc);
    const bool t0blk = ((m0 & 2047) == 0);
#pragma unroll
    for (int nt = 0; nt < 2; nt++) {
      const int n = w * 32 + nt * 16 + lm;
      const float bv = b2[n];
      float sl = 0.f, sq = 0.f, r0v = 0.f;
#pragma unroll
      for (int mt = 0; mt < 4; mt++)
#pragma unroll
        for (int r = 0; r < 4; r++) {
          float v = fmaxf(acc[mt][nt][r] + bv, 0.f);
          sl += v; sq += v * v;
          if (mt == 0 && r == 0) r0v = v;
        }
      sl += __shfl_xor(sl, 16); sl += __shfl_xor(sl, 32);
      sq += __shfl_xor(sq, 16); sq += __shfl_xor(sq, 32);
      if (lq == 0) {
        sSum[n] = sl; sSq[n] = sq;
        if (t0blk) zb0[(m0 >> 11) * 128 + n] = f2bf(r0v);
      }
    }
  }
  __syncthreads();
  const int rep = blockIdx.x & 7;
  if (tid < 128) atomicAdd(&st[rep * 256 + tid], sSum[tid]);
  else atomicAdd(&st[rep * 256 + tid], sSq[tid - 128]);
}

// ---------------- fused decoder: 64-row tile; hb -> relu MLP x2 -> fp32 out ----------------
__global__ __launch_bounds__(256, 2) void dec_k(const u16* __restrict__ hb, const u16* __restrict__ wt,
                                                const float* __restrict__ b0, const float* __restrict__ b1,
                                                const float* __restrict__ b2, float* __restrict__ out) {
  __shared__ __align__(16) u16 bufA[64 * 264];
  __shared__ __align__(16) u16 bufB[64 * 264];
  const int tid = threadIdx.x, w = tid >> 6, l = tid & 63, lm = l & 15, lq = l >> 4;
  const int m0 = blockIdx.x * 64;
  // stage hb: 64 rows x 128 bf16, stride 136 (1024 uint4 = full tile)
  for (int i = tid; i < 1024; i += 256) {
    int row = i >> 4, c8 = i & 15;
    *(uint4*)&bufA[row * 136 + c8 * 8] = *(const uint4*)&hb[(size_t)(m0 + row) * 128 + c8 * 8];
  }
  __syncthreads();
  // L0: 128 -> 256
  {
    f32x4 acc[4][4];
#pragma unroll
    for (int i = 0; i < 4; i++)
#pragma unroll
      for (int j = 0; j < 4; j++) acc[i][j] = (f32x4){0.f, 0.f, 0.f, 0.f};
    layer<128, 136, 4, 4>(bufA, wt + OD0, w * 64, lm, lq, acc);
    __syncthreads();
#pragma unroll
    for (int nt = 0; nt < 4; nt++) {
      const int n = w * 64 + nt * 16 + lm;
      const float bv = b0[n];
#pragma unroll
      for (int mt = 0; mt < 4; mt++)
#pragma unroll
        for (int r = 0; r < 4; r++) {
          const int m = mt * 16 + lq * 4 + r;
          bufB[m * 264 + n] = f2bf(fmaxf(acc[mt][nt][r] + bv, 0.f));
        }
    }
  }
  __syncthreads();
  // L1: 256 -> 256
  {
    f32x4 acc[4][4];
#pragma unroll
    for (int i = 0; i < 4; i++)
#pragma unroll
      for (int j = 0; j < 4; j++) acc[i][j] = (f32x4){0.f, 0.f, 0.f, 0.f};
    layer<256, 264, 4, 4>(bufB, wt + OD1, w * 64, lm, lq, acc);
    __syncthreads();
#pragma unroll
    for (int nt = 0; nt < 4; nt++) {
      const int n = w * 64 + nt * 16 + lm;
      const float bv = b1[n];
#pragma unroll
      for (int mt = 0; mt < 4; mt++)
#pragma unroll
        for (int r = 0; r < 4; r++) {
          const int m = mt * 16 + lq * 4 + r;
          bufA[m * 264 + n] = f2bf(fmaxf(acc[mt][nt][r] + bv, 0.f));
        }
    }
  }
  __syncthreads();
  // L2: 256 -> 64, fp32 out
  {
    f32x4 acc[4][1];
#pragma unroll
    for (int i = 0; i < 4; i++) acc[i][0] = (f32x4){0.f, 0.f, 0.f, 0.f};
    layer<256, 264, 1, 4>(bufA, wt + OD2, w * 16, lm, lq, acc);
    const int n = w * 16 + lm;
    const float bv = b2[n];
#pragma unroll
    for (int mt = 0; mt < 4; mt++)
#pragma unroll
      for (int r = 0; r < 4; r++) {
        const int m = mt * 16 + lq * 4 + r;
        out[(size_t)(m0 + m) * 64 + n] = acc[mt][0][r] + bv;
      }
  }
}

// ---------------- finalize: sum 8 stat replicas -> normalize z[:,0,:] -> yb[0] seed ----------------
__global__ __launch_bounds__(128) void finalize_k(const float* __restrict__ st, const u16* __restrict__ zb0,
                                                  const float* __restrict__ gam, const float* __restrict__ bet,
                                                  u16* __restrict__ yb) {
  const int ch = threadIdx.x;
  float s = 0.f, q = 0.f;
#pragma unroll
  for (int rep = 0; rep < 8; rep++) {
    s += st[rep * 256 + ch];
    q += st[rep * 256 + 128 + ch];
  }
  const float mean = s * (1.f / 65536.f);
  const float var = q * (1.f / 65536.f) - mean * mean;
  const float sc = rsqrtf(var + 1e-5f) * gam[ch];
  const float sh = bet[ch] - mean * sc;
  for (int b = 0; b < 32; b++) {
    float z = bf2f(zb0[b * 128 + ch]);
    yb[b * 128 + ch] = f2bf(z * sc + sh);
  }
}

// ---------------- matrix powers (fp32): A^{p+mi+1} = A^p * A^{mi+1} ----------------
__global__ __launch_bounds__(256) void pow_round_k(float* __restrict__ powR, u16* __restrict__ powT,
                                                   int p, int mi_base) {
  const int mi = mi_base + (blockIdx.x >> 2), nc = blockIdx.x & 3;
  const float* Rp = powR + (size_t)p * 16384;
  const float* Rm = powR + (size_t)(mi + 1) * 16384;
  float* Ro = powR + (size_t)(p + mi + 1) * 16384;
  u16* To = powT + (size_t)(p + mi + 1) * 16384;
  __shared__ __align__(16) float RpS[128 * 132];
  __shared__ __align__(16) float RmS[128 * 36];
  const int tid = threadIdx.x;
  for (int i = tid; i < 4096; i += 256) {
    int r = i >> 5, c4 = i & 31;
    *(float4*)&RpS[r * 132 + c4 * 4] = *(const float4*)&Rp[r * 128 + c4 * 4];
  }
  for (int i = tid; i < 1024; i += 256) {
    int r = i >> 3, c4 = i & 7;
    *(float4*)&RmS[r * 36 + c4 * 4] = *(const float4*)&Rm[r * 128 + nc * 32 + c4 * 4];
  }
  __syncthreads();
  const int tc = tid & 7, tr = tid >> 3;
  float acc[4][4];
#pragma unroll
  for (int i = 0; i < 4; i++)
#pragma unroll
    for (int j = 0; j < 4; j++) acc[i][j] = 0.f;
  for (int kk = 0; kk < 128; kk++) {
    const float4 bv = *(const float4*)&RmS[kk * 36 + tc * 4];
#pragma unroll
    for (int i = 0; i < 4; i++) {
      const float av = RpS[(tr * 4 + i) * 132 + kk];
      acc[i][0] += av * bv.x; acc[i][1] += av * bv.y;
      acc[i][2] += av * bv.z; acc[i][3] += av * bv.w;
    }
  }
#pragma unroll
  for (int i = 0; i < 4; i++)
#pragma unroll
    for (int j = 0; j < 4; j++) {
      const int row = tr * 4 + i, col = nc * 32 + tc * 4 + j;
      Ro[row * 128 + col] = acc[i][j];
      To[col * 128 + row] = f2bf(acc[i][j]);
    }
}

// ---------------- phase 1: local scans, 256 chunks x 8 steps, bu on the fly ----------------
__global__ __launch_bounds__(256) void phase1_k(const float* __restrict__ in, const float* __restrict__ Bd,
                                                const u16* __restrict__ powT, u16* __restrict__ lb,
                                                u16* __restrict__ yb) {
  __shared__ __align__(16) u16 hS[2][32 * 136];
  __shared__ __align__(16) u16 buS[32 * 136];
  const int tid = threadIdx.x, c = blockIdx.x;
  const int w = tid >> 6, l = tid & 63, lm = l & 15, lq = l >> 4;
  const u16* T1 = powT + 16384;  // A^T
  short8 bfr[2][4];
#pragma unroll
  for (int nt = 0; nt < 2; nt++)
#pragma unroll
    for (int ks = 0; ks < 4; ks++) {
      int n = (w * 2 + nt) * 16 + lm, k0 = ks * 32 + lq * 8;
      bfr[nt][ks] = *(const short8*)&T1[n * 128 + k0];
    }
  const int r0 = tid >> 4, ch = tid & 15;
  float dv[8];
#pragma unroll
  for (int j = 0; j < 8; j++) {
    float d = Bd[ch * 8 + j];
    dv[j] = fminf(0.95f, fmaxf(-0.95f, d));
  }
  const float* u0 = in + (size_t)r0 * 2048 * 320 + (size_t)(c * 8) * 320 + 192 + ch * 8;
  const float* u1 = in + (size_t)(r0 + 16) * 2048 * 320 + (size_t)(c * 8) * 320 + 192 + ch * 8;
  float4 p0 = *(const float4*)u0, p0b = *(const float4*)(u0 + 4);
  float4 p1 = *(const float4*)u1, p1b = *(const float4*)(u1 + 4);
  for (int tau = 0; tau < 8; tau++) {
    const int t = c * 8 + tau;
    short8 s0, s1;
    s0[0] = (short)f2bf(p0.x * dv[0]); s0[1] = (short)f2bf(p0.y * dv[1]);
    s0[2] = (short)f2bf(p0.z * dv[2]); s0[3] = (short)f2bf(p0.w * dv[3]);
    s0[4] = (short)f2bf(p0b.x * dv[4]); s0[5] = (short)f2bf(p0b.y * dv[5]);
    s0[6] = (short)f2bf(p0b.z * dv[6]); s0[7] = (short)f2bf(p0b.w * dv[7]);
    s1[0] = (short)f2bf(p1.x * dv[0]); s1[1] = (short)f2bf(p1.y * dv[1]);
    s1[2] = (short)f2bf(p1.z * dv[2]); s1[3] = (short)f2bf(p1.w * dv[3]);
    s1[4] = (short)f2bf(p1b.x * dv[4]); s1[5] = (short)f2bf(p1b.y * dv[5]);
    s1[6] = (short)f2bf(p1b.z * dv[6]); s1[7] = (short)f2bf(p1b.w * dv[7]);
    *(short8*)&buS[r0 * 136 + ch * 8] = s0;
    *(short8*)&buS[(r0 + 16) * 136 + ch * 8] = s1;
    __syncthreads();
    if (tau < 7) {
      const float* q0 = u0 + (tau + 1) * 320;
      const float* q1 = u1 + (tau + 1) * 320;
      p0 = *(const float4*)q0; p0b = *(const float4*)(q0 + 4);
      p1 = *(const float4*)q1; p1b = *(const float4*)(q1 + 4);
    }
    f32x4 acc[2][2];
#pragma unroll
    for (int mt = 0; mt < 2; mt++)
#pragma unroll
      for (int nt = 0; nt < 2; nt++) acc[mt][nt] = (f32x4){0.f, 0.f, 0.f, 0.f};
    if (tau > 0) {
#pragma unroll
      for (int ks = 0; ks < 4; ks++) {
        const int k0 = ks * 32 + lq * 8;
#pragma unroll
        for (int mt = 0; mt < 2; mt++) {
          short8 a = *(const short8*)&hS[tau & 1][(mt * 16 + lm) * 136 + k0];
          acc[mt][0] = mfma16(a, bfr[0][ks], acc[mt][0]);
          acc[mt][1] = mfma16(a, bfr[1][ks], acc[mt][1]);
        }
      }
    }
#pragma unroll
    for (int mt = 0; mt < 2; mt++)
#pragma unroll
      for (int nt = 0; nt < 2; nt++) {
        const int n = (w * 2 + nt) * 16 + lm;
#pragma unroll
        for (int r = 0; r < 4; r++) {
          const int m = mt * 16 + lq * 4 + r;
          float v = acc[mt][nt][r] + bf2f(buS[m * 136 + n]);
          u16 hv = f2bf(v);
          hS[(tau + 1) & 1][m * 136 + n] = hv;
          lb[((size_t)t * 32 + m) * 128 + n] = hv;
          if (tau == 7 && c < 255) yb[((size_t)(c + 1)) * 4096 + m * 128 + n] = hv;
        }
      }
    __syncthreads();
  }
}

// ---------------- fused 3-term carry resolve:
// ins[c] = y[c] + y[c-1]A^8 + (y[c-2] + y[c-3]A^8)A^16   (trunc >= A^32 ~ 1e-8)
__global__ __launch_bounds__(256) void kslf_k(const u16* __restrict__ yb, const u16* __restrict__ powT,
                                              u16* __restrict__ ins) {
  const int c = blockIdx.x, tid = threadIdx.x;
  if (c == 0) {
    for (int i = tid; i < 512; i += 256) ((uint4*)ins)[i] = ((const uint4*)yb)[i];
    return;
  }
  __shared__ __align__(16) u16 sA[32 * 136];
  __shared__ __align__(16) u16 sW[32 * 136];
  const int w = tid >> 6, l = tid & 63, lm = l & 15, lq = l >> 4;
  const u16* A8 = powT + (size_t)8 * 16384;
  short8 f8[2][4];
#pragma unroll
  for (int nt = 0; nt < 2; nt++)
#pragma unroll
    for (int ks = 0; ks < 4; ks++)
      f8[nt][ks] = *(const short8*)&A8[((w * 2 + nt) * 16 + lm) * 128 + ks * 32 + lq * 8];
  const bool havew = (c >= 2);
  if (c >= 3) {
    for (int i = tid; i < 512; i += 256) {
      int row = i >> 4, chh = i & 15;
      *(uint4*)&sA[row * 136 + chh * 8] = *(const uint4*)&yb[(size_t)(c - 3) * 4096 + row * 128 + chh * 8];
    }
    __syncthreads();
    f32x4 accw[2][2];
#pragma unroll
    for (int mt = 0; mt < 2; mt++)
#pragma unroll
      for (int nt = 0; nt < 2; nt++)
#pragma unroll
        for (int r = 0; r < 4; r++)
          accw[mt][nt][r] = bf2f(yb[(size_t)(c - 2) * 4096 + (mt * 16 + lq * 4 + r) * 128 + (w * 2 + nt) * 16 + lm]);
#pragma unroll
    for (int ks = 0; ks < 4; ks++) {
      const int k0 = ks * 32 + lq * 8;
#pragma unroll
      for (int mt = 0; mt < 2; mt++) {
        short8 a = *(const short8*)&sA[(mt * 16 + lm) * 136 + k0];
        accw[mt][0] = mfma16(a, f8[0][ks], accw[mt][0]);
        accw[mt][1] = mfma16(a, f8[1][ks], accw[mt][1]);
      }
    }
#pragma unroll
    for (int mt = 0; mt < 2; mt++)
#pragma unroll
      for (int nt = 0; nt < 2; nt++)
#pragma unroll
        for (int r = 0; r < 4; r++)
          sW[(mt * 16 + lq * 4 + r) * 136 + (w * 2 + nt) * 16 + lm] = f2bf(accw[mt][nt][r]);
  } else if (c == 2) {
    for (int i = tid; i < 512; i += 256) {
      int row = i >> 4, chh = i & 15;
      *(uint4*)&sW[row * 136 + chh * 8] = *(const uint4*)&yb[row * 128 + chh * 8];  // y[0]
    }
  }
  __syncthreads();
  // stage y[c-1]
  for (int i = tid; i < 512; i += 256) {
    int row = i >> 4, chh = i & 15;
    *(uint4*)&sA[row * 136 + chh * 8] = *(const uint4*)&yb[(size_t)(c - 1) * 4096 + row * 128 + chh * 8];
  }
  __syncthreads();
  f32x4 acc[2][2];
#pragma unroll
  for (int mt = 0; mt < 2; mt++)
#pragma unroll
    for (int nt = 0; nt < 2; nt++)
#pragma unroll
      for (int r = 0; r < 4; r++)
        acc[mt][nt][r] = bf2f(yb[(size_t)c * 4096 + (mt * 16 + lq * 4 + r) * 128 + (w * 2 + nt) * 16 + lm]);
#pragma unroll
  for (int ks = 0; ks < 4; ks++) {
    const int k0 = ks * 32 + lq * 8;
#pragma unroll
    for (int mt = 0; mt < 2; mt++) {
      short8 a = *(const short8*)&sA[(mt * 16 + lm) * 136 + k0];
      acc[mt][0] = mfma16(a, f8[0][ks], acc[mt][0]);
      acc[mt][1] = mfma16(a, f8[1][ks], acc[mt][1]);
    }
  }
  if (havew) {
    const u16* A16 = powT + (size_t)16 * 16384;
    short8 f16a[2][4];
#pragma unroll
    for (int nt = 0; nt < 2; nt++)
#pragma unroll
      for (int ks = 0; ks < 4; ks++)
        f16a[nt][ks] = *(const short8*)&A16[((w * 2 + nt) * 16 + lm) * 128 + ks * 32 + lq * 8];
#pragma unroll
    for (int ks = 0; ks < 4; ks++) {
      const int k0 = ks * 32 + lq * 8;
#pragma unroll
      for (int mt = 0; mt < 2; mt++) {
        short8 a = *(const short8*)&sW[(mt * 16 + lm) * 136 + k0];
        acc[mt][0] = mfma16(a, f16a[0][ks], acc[mt][0]);
        acc[mt][1] = mfma16(a, f16a[1][ks], acc[mt][1]);
      }
    }
  }
#pragma unroll
  for (int mt = 0; mt < 2; mt++)
#pragma unroll
    for (int nt = 0; nt < 2; nt++)
#pragma unroll
      for (int r = 0; r < 4; r++)
        ins[(size_t)c * 4096 + (mt * 16 + lq * 4 + r) * 128 + (w * 2 + nt) * 16 + lm] = f2bf(acc[mt][nt][r]);
}

// ---------------- phase 3: h[c*8+tau] = ins_c @ A^{tau+1} + lb ----------------
__global__ __launch_bounds__(256) void phase3_k(const u16* __restrict__ ins, const u16* __restrict__ powT,
                                                const u16* __restrict__ lb, u16* __restrict__ hb) {
  __shared__ __align__(16) u16 inS[32 * 136];
  const int c = blockIdx.x >> 3, tau = blockIdx.x & 7, t = c * 8 + tau;
  const int tid = threadIdx.x;
  const int w = tid >> 6, l = tid & 63, lm = l & 15, lq = l >> 4;
  const u16* Tj = powT + (size_t)(tau + 1) * 16384;
  short8 bfr[2][4];
#pragma unroll
  for (int nt = 0; nt < 2; nt++)
#pragma unroll
    for (int ks = 0; ks < 4; ks++) {
      int n = (w * 2 + nt) * 16 + lm, k0 = ks * 32 + lq * 8;
      bfr[nt][ks] = *(const short8*)&Tj[n * 128 + k0];
    }
  for (int i = tid; i < 512; i += 256) {
    int row = i >> 4, ch = i & 15;
    *(uint4*)&inS[row * 136 + ch * 8] = *(const uint4*)&ins[(size_t)c * 4096 + row * 128 + ch * 8];
  }
  __syncthreads();
  f32x4 acc[2][2];
#pragma unroll
  for (int mt = 0; mt < 2; mt++)
#pragma unroll
    for (int nt = 0; nt < 2; nt++) acc[mt][nt] = (f32x4){0.f, 0.f, 0.f, 0.f};
#pragma unroll
  for (int ks = 0; ks < 4; ks++) {
    const int k0 = ks * 32 + lq * 8;
#pragma unroll
    for (int mt = 0; mt < 2; mt++) {
      short8 a = *(const short8*)&inS[(mt * 16 + lm) * 136 + k0];
      acc[mt][0] = mfma16(a, bfr[0][ks], acc[mt][0]);
      acc[mt][1] = mfma16(a, bfr[1][ks], acc[mt][1]);
    }
  }
#pragma unroll
  for (int mt = 0; mt < 2; mt++)
#pragma unroll
    for (int nt = 0; nt < 2; nt++) {
      const int n = (w * 2 + nt) * 16 + lm;
#pragma unroll
      for (int r = 0; r < 4; r++) {
        const int m = mt * 16 + lq * 4 + r;
        float v = acc[mt][nt][r] + bf2f(lb[((size_t)t * 32 + m) * 128 + n]);
        hb[((size_t)m * 2048 + t) * 128 + n] = f2bf(v);
      }
    }
}

// ---------------- launcher ----------------
extern "C" void kernel_launch(void* const* d_in, const int* in_sizes, int n_in,
                              void* d_out, int out_size, void* d_ws, size_t ws_size,
                              hipStream_t stream) {
  const float* in  = (const float*)d_in[0];
  const float* ew0 = (const float*)d_in[1];  const float* eb0 = (const float*)d_in[2];
  const float* ew1 = (const float*)d_in[3];  const float* eb1 = (const float*)d_in[4];
  const float* ew2 = (const float*)d_in[5];  const float* eb2 = (const float*)d_in[6];
  const float* gam = (const float*)d_in[7];  const float* bet = (const float*)d_in[8];
  const float* Aw  = (const float*)d_in[9];  const float* Bd  = (const float*)d_in[10];
  const float* dw0 = (const float*)d_in[11]; const float* db0 = (const float*)d_in[12];
  const float* dw1 = (const float*)d_in[13]; const float* db1 = (const float*)d_in[14];
  const float* dw2 = (const float*)d_in[15]; const float* db2 = (const float*)d_in[16];

  char* ws = (char*)d_ws;
  u16*   hb   = (u16*)(ws + OFF_HB);
  u16*   lbuf = (u16*)(ws + OFF_LB);
  u16*   wt   = (u16*)(ws + OFF_WT);
  float* powR = (float*)(ws + OFF_POWR);
  u16*   powT = (u16*)(ws + OFF_POWT);
  float* st   = (float*)(ws + OFF_ST);
  u16*   zb0  = (u16*)(ws + OFF_ZB0);
  u16*   yb   = (u16*)(ws + OFF_YB);
  u16*   ins  = (u16*)(ws + OFF_INS);
  float* out  = (float*)d_out;

  hipMemsetAsync(ws + OFF_ST, 0, 8192, stream);
  convw_k<<<960, 256, 0, stream>>>(ew0, ew1, ew2, dw0, dw1, dw2, Aw, wt, powR, powT);

  // A powers: 1..8 and 16
  pow_round_k<<<4, 256, 0, stream>>>(powR, powT, 1, 0);
  pow_round_k<<<8, 256, 0, stream>>>(powR, powT, 2, 0);
  pow_round_k<<<16, 256, 0, stream>>>(powR, powT, 4, 0);
  pow_round_k<<<4, 256, 0, stream>>>(powR, powT, 8, 7);   // A^16

  // local scans (independent of encoder)
  phase1_k<<<256, 256, 0, stream>>>(in, Bd, powT, lbuf, yb);

  // fused encoder (stats + z[:,0,:] only)
  enc_k<<<1024, 256, 0, stream>>>(in, wt, eb0, eb1, eb2, st, zb0);
  finalize_k<<<1, 128, 0, stream>>>(st, zb0, gam, bet, yb);

  // carry resolve + recombine
  kslf_k<<<256, 256, 0, stream>>>(yb, powT, ins);
  phase3_k<<<2048, 256, 0, stream>>>(ins, powT, lbuf, hb);

  // fused decoder
  dec_k<<<1024, 256, 0, stream>>>(hb, wt, db0, db1, db2, out);
}